// Round 3
// baseline (2496.113 us; speedup 1.0000x reference)
//
#include <hip/hip_runtime.h>
#include <hip/hip_bf16.h>

typedef __hip_bfloat16 bf16;

#define BB 4
#define HH 240
#define WW 320
#define CG 64
#define NCO 24
#define HWSZ (HH*WW)

// Runtime-polymorphic input load: isbf chosen per-kernel from the scalar input.
__device__ __forceinline__ float ldF(const void* __restrict__ p, long i, int isbf) {
    if (isbf) return __bfloat162float(((const bf16*)p)[i]);
    return ((const float*)p)[i];
}

__device__ __forceinline__ int detect_bf16(const void* asc) {
    // aff_scale_const == 4.0f. fp32 little-endian low uint16 of 0x40800000 is 0x0000;
    // bf16 encoding of 4.0 is 0x4080. Nonzero => bf16 inputs.
    return ((const unsigned short*)asc)[0] != 0;
}

// ---------------------------------------------------------------------------
// Kernel 1: bilinear 2x upsample (jax.image.resize == edge-renormalized ==
// clamped bilinear at src = 0.5*o - 0.25), input -> fp32 ws [b][c][i][j]
// ---------------------------------------------------------------------------
__global__ __launch_bounds__(256) void upsample_kernel(const void* __restrict__ tin,
                                                       const void* __restrict__ asc,
                                                       float* __restrict__ fea) {
    int isbf = detect_bf16(asc);
    int idx = blockIdx.x * 256 + threadIdx.x;
    if (idx >= BB * 8 * HWSZ) return;
    int j = idx % WW;
    int rest = idx / WW;
    int i = rest % HH;
    int bc = rest / HH;  // b*8+c
    float sy = 0.5f * (float)i - 0.25f;
    float sx = 0.5f * (float)j - 0.25f;
    float y0f = floorf(sy), x0f = floorf(sx);
    float wy = sy - y0f, wx = sx - x0f;
    int y0 = (int)y0f, x0 = (int)x0f;
    int y0c = min(max(y0, 0), 119), y1c = min(max(y0 + 1, 0), 119);
    int x0c = min(max(x0, 0), 159), x1c = min(max(x0 + 1, 0), 159);
    long base = (long)bc * 120 * 160;
    float v00 = ldF(tin, base + y0c * 160 + x0c, isbf);
    float v01 = ldF(tin, base + y0c * 160 + x1c, isbf);
    float v10 = ldF(tin, base + y1c * 160 + x0c, isbf);
    float v11 = ldF(tin, base + y1c * 160 + x1c, isbf);
    fea[idx] = (1.f - wy) * ((1.f - wx) * v00 + wx * v01)
             + wy * ((1.f - wx) * v10 + wx * v11);
}

// ---------------------------------------------------------------------------
// Kernel 2: 3x3 conv (cross-correlation, NCHW/OIHW), 64 -> 24, pad 1, + bias.
// Output fp32 pixel-major: oa[((b*H+i)*W+j)*24 + c]
// ---------------------------------------------------------------------------
__global__ __launch_bounds__(256) void conv_kernel(const void* __restrict__ g,
                                                   const void* __restrict__ w,
                                                   const void* __restrict__ bias,
                                                   const void* __restrict__ asc,
                                                   float* __restrict__ oa) {
    int isbf = detect_bf16(asc);
    int b = blockIdx.z;
    int i0 = blockIdx.y * 16;
    int j0 = blockIdx.x * 32;
    int tx = threadIdx.x & 31;
    int ty = threadIdx.x >> 5;  // 0..7

    __shared__ float gl[8][18][34];
    __shared__ float wl[8][24][12];

    float acc0[NCO], acc1[NCO];
#pragma unroll
    for (int c = 0; c < NCO; c++) {
        float bv = ldF(bias, c, isbf);
        acc0[c] = bv; acc1[c] = bv;
    }

    for (int ci0 = 0; ci0 < CG; ci0 += 8) {
        __syncthreads();
        for (int idx = threadIdx.x; idx < 8 * 24 * 9; idx += 256) {
            int t = idx % 9;
            int rest = idx / 9;
            int co = rest % 24;
            int cc = rest / 24;
            wl[cc][co][t] = ldF(w, (long)(co * CG + ci0 + cc) * 9 + t, isbf);
        }
        for (int idx = threadIdx.x; idx < 8 * 18 * 34; idx += 256) {
            int c2 = idx % 34;
            int rest = idx / 34;
            int r = rest % 18;
            int cc = rest / 18;
            int gi = i0 - 1 + r;
            int gj = j0 - 1 + c2;
            float v = 0.f;
            if (gi >= 0 && gi < HH && gj >= 0 && gj < WW)
                v = ldF(g, ((long)(b * CG + ci0 + cc) * HH + gi) * WW + gj, isbf);
            gl[cc][r][c2] = v;
        }
        __syncthreads();
#pragma unroll
        for (int cc = 0; cc < 8; cc++) {
            float ga[3][3], gb[3][3];
#pragma unroll
            for (int dy = 0; dy < 3; dy++)
#pragma unroll
                for (int dx = 0; dx < 3; dx++) {
                    ga[dy][dx] = gl[cc][ty + dy][tx + dx];
                    gb[dy][dx] = gl[cc][ty + 8 + dy][tx + dx];
                }
#pragma unroll
            for (int co = 0; co < NCO; co++) {
                float s0 = 0.f, s1 = 0.f;
#pragma unroll
                for (int t = 0; t < 9; t++) {
                    float wv = wl[cc][co][t];
                    s0 += wv * ga[t / 3][t % 3];
                    s1 += wv * gb[t / 3][t % 3];
                }
                acc0[co] += s0;
                acc1[co] += s1;
            }
        }
    }
    int ia = i0 + ty, ib = i0 + ty + 8;
    int j = j0 + tx;
    float4* p0 = (float4*)&oa[(((size_t)b * HH + ia) * WW + j) * NCO];
    float4* p1 = (float4*)&oa[(((size_t)b * HH + ib) * WW + j) * NCO];
#pragma unroll
    for (int q = 0; q < 6; q++) {
        p0[q] = make_float4(acc0[4 * q], acc0[4 * q + 1], acc0[4 * q + 2], acc0[4 * q + 3]);
        p1[q] = make_float4(acc1[4 * q], acc1[4 * q + 1], acc1[4 * q + 2], acc1[4 * q + 3]);
    }
}

// ---------------------------------------------------------------------------
// bilinear with zero padding outside (reference _bilinear_zeros semantics)
// ---------------------------------------------------------------------------
__device__ __forceinline__ float bil_zero_f32(const float* __restrict__ img,
                                              float x, float y, int Hh, int Wwd) {
    float x0f = floorf(x), y0f = floorf(y);
    float wx = x - x0f, wy = y - y0f;
    int x0 = (int)x0f, y0 = (int)y0f;
    float v00 = 0.f, v01 = 0.f, v10 = 0.f, v11 = 0.f;
    bool xv0 = (x0 >= 0) && (x0 < Wwd);
    bool xv1 = (x0 + 1 >= 0) && (x0 + 1 < Wwd);
    if (y0 >= 0 && y0 < Hh) {
        const float* r = img + (size_t)y0 * Wwd;
        if (xv0) v00 = r[x0];
        if (xv1) v01 = r[x0 + 1];
    }
    if (y0 + 1 >= 0 && y0 + 1 < Hh) {
        const float* r = img + (size_t)(y0 + 1) * Wwd;
        if (xv0) v10 = r[x0];
        if (xv1) v11 = r[x0 + 1];
    }
    return (1.f - wy) * ((1.f - wx) * v00 + wx * v01)
         + wy * ((1.f - wx) * v10 + wx * v11);
}

__device__ __forceinline__ float bil_zero_poly(const void* __restrict__ img, long base,
                                               float x, float y, int Hh, int Wwd, int isbf) {
    float x0f = floorf(x), y0f = floorf(y);
    float wx = x - x0f, wy = y - y0f;
    int x0 = (int)x0f, y0 = (int)y0f;
    float v00 = 0.f, v01 = 0.f, v10 = 0.f, v11 = 0.f;
    bool xv0 = (x0 >= 0) && (x0 < Wwd);
    bool xv1 = (x0 + 1 >= 0) && (x0 + 1 < Wwd);
    if (y0 >= 0 && y0 < Hh) {
        long r = base + (long)y0 * Wwd;
        if (xv0) v00 = ldF(img, r + x0, isbf);
        if (xv1) v01 = ldF(img, r + x0 + 1, isbf);
    }
    if (y0 + 1 >= 0 && y0 + 1 < Hh) {
        long r = base + (long)(y0 + 1) * Wwd;
        if (xv0) v10 = ldF(img, r + x0, isbf);
        if (xv1) v11 = ldF(img, r + x0 + 1, isbf);
    }
    return (1.f - wy) * ((1.f - wx) * v00 + wx * v01)
         + wy * ((1.f - wx) * v10 + wx * v11);
}

// ---------------------------------------------------------------------------
// Kernel 3: scrambled cosine-affinity gather + conf + TGASS + softmax + writes.
// Inversion of the reference's raw reshape (re-derived symbolically, R2):
//   cos_w[b,c,i,j] = sum_{n<8} fea_up[b,n,i,j] * bil(fea_up[b, i/30], px, py)
//   source grid pixel (pi,qj) = ((i%30)*8 + j/40, (j%40)*8 + n)
//   px = oa[pi,qj,2c] + add, py = oa[pi,qj,2c+1] + add, add = (c<4 ? pi : qj)
// Outputs are fp32 (reference dtype).
// ---------------------------------------------------------------------------
__global__ __launch_bounds__(256) void final_kernel(const float* __restrict__ oa,
                                                    const float* __restrict__ fea,
                                                    const void* __restrict__ conf_in,
                                                    const void* __restrict__ asc_p,
                                                    float* __restrict__ out) {
    int isbf = detect_bf16(asc_p);
    int idx = blockIdx.x * 256 + threadIdx.x;
    if (idx >= BB * HWSZ) return;
    int j = idx % WW;
    int rest = idx / WW;
    int i = rest % HH;
    int b = rest / HH;

    const float* feaB = fea + (size_t)b * 8 * HWSZ;
    float f[8];
#pragma unroll
    for (int n = 0; n < 8; n++)
        f[n] = feaB[(size_t)n * HWSZ + (size_t)i * WW + j];

    int c_img = i / 30;
    int pi = (i % 30) * 8 + j / 40;
    int pj0 = (j % 40) * 8;
    const float* feaC = feaB + (size_t)c_img * HWSZ;

    float cos_acc[8];
#pragma unroll
    for (int c = 0; c < 8; c++) cos_acc[c] = 0.f;

#pragma unroll
    for (int n = 0; n < 8; n++) {
        int qj = pj0 + n;
        const float4* oq = (const float4*)&oa[(((size_t)b * HH + pi) * WW + qj) * NCO];
        float4 o0 = oq[0], o1 = oq[1], o2 = oq[2], o3 = oq[3];
        float off[16] = {o0.x, o0.y, o0.z, o0.w, o1.x, o1.y, o1.z, o1.w,
                         o2.x, o2.y, o2.z, o2.w, o3.x, o3.y, o3.z, o3.w};
        float fn = f[n];
#pragma unroll
        for (int c = 0; c < 8; c++) {
            float add = (c < 4) ? (float)pi : (float)qj;
            float px = off[2 * c] + add;
            float py = off[2 * c + 1] + add;
            cos_acc[c] += fn * bil_zero_f32(feaC, px, py, HH, WW);
        }
    }

    const float4* op = (const float4*)&oa[(((size_t)b * HH + i) * WW + j) * NCO];
    float own[24];
#pragma unroll
    for (int q = 0; q < 6; q++) {
        float4 v = op[q];
        own[4 * q] = v.x; own[4 * q + 1] = v.y; own[4 * q + 2] = v.z; own[4 * q + 3] = v.w;
    }

    float asc = ldF(asc_p, 0, isbf) + 1e-8f;
    long cbase = (long)b * HWSZ;

    float a[8];
    float ssum = 0.f;
#pragma unroll
    for (int c = 0; c < 8; c++) {
        float v = own[16 + c] * cos_acc[c];
        v = tanhf(v) / asc;
        float py2 = own[2 * c] + (float)i;       // channel 0 = dy
        float px2 = own[2 * c + 1] + (float)j;   // channel 1 = dx
        float cf = bil_zero_poly(conf_in, cbase, px2, py2, HH, WW, isbf);
        v *= cf;
        a[c] = v;
        ssum += fabsf(v);
    }
    ssum += 1e-4f;
    ssum = fmaxf(ssum, 1.0f);
    float inv = 1.0f / ssum;
    float asum = 0.f;
#pragma unroll
    for (int c = 0; c < 8; c++) { a[c] *= inv; asum += a[c]; }
    float aref = 1.0f - asum;

    float vals[9];
#pragma unroll
    for (int c = 0; c < 4; c++) vals[c] = a[c];
    vals[4] = aref;
#pragma unroll
    for (int c = 4; c < 8; c++) vals[c + 1] = a[c];
    float m = vals[0];
#pragma unroll
    for (int k = 1; k < 9; k++) m = fmaxf(m, vals[k]);
    float es = 0.f;
#pragma unroll
    for (int k = 0; k < 9; k++) { vals[k] = __expf(vals[k] - m); es += vals[k]; }
    float ei = 1.0f / es;

    size_t pix = (size_t)i * WW + j;
    size_t base_o = (size_t)b * 18 * HWSZ + pix;
#pragma unroll
    for (int ch = 0; ch < 18; ch++) {
        float v;
        if (ch < 8) v = own[ch];
        else if (ch < 10) v = 0.f;
        else v = own[ch - 2];
        out[base_o + (size_t)ch * HWSZ] = v;
    }
    float* aff_out = out + (size_t)BB * 18 * HWSZ;
    size_t base_a = (size_t)b * 9 * HWSZ + pix;
#pragma unroll
    for (int k = 0; k < 9; k++)
        aff_out[base_a + (size_t)k * HWSZ] = vals[k] * ei;
}

// ---------------------------------------------------------------------------
extern "C" void kernel_launch(void* const* d_in, const int* in_sizes, int n_in,
                              void* d_out, int out_size, void* d_ws, size_t ws_size,
                              hipStream_t stream) {
    const void* guidance = d_in[0];
    const void* gtconf   = d_in[1];
    const void* tgt      = d_in[2];
    const void* conv_w   = d_in[3];
    const void* conv_b   = d_in[4];
    const void* asc      = d_in[5];

    float* oa  = (float*)d_ws;                        // B*H*W*24 fp32
    float* fea = oa + (size_t)BB * HWSZ * NCO;        // B*8*H*W fp32
    float* out = (float*)d_out;

    int n_up = BB * 8 * HWSZ;
    upsample_kernel<<<(n_up + 255) / 256, 256, 0, stream>>>(tgt, asc, fea);

    dim3 cgrid(WW / 32, HH / 16, BB);
    conv_kernel<<<cgrid, 256, 0, stream>>>(guidance, conv_w, conv_b, asc, oa);

    int n_fin = BB * HWSZ;
    final_kernel<<<(n_fin + 255) / 256, 256, 0, stream>>>(oa, fea, gtconf, asc, out);
}

// Round 4
// 711.590 us; speedup vs baseline: 3.5078x; 3.5078x over previous
//
#include <hip/hip_runtime.h>
#include <hip/hip_bf16.h>

typedef __hip_bfloat16 bf16;

#define BB 4
#define HH 240
#define WW 320
#define CG 64
#define NCO 24
#define HWSZ (HH*WW)

// Runtime-polymorphic input load (compile-time flavor via template).
template<int ISBF>
__device__ __forceinline__ float ldT(const void* __restrict__ p, long i) {
    if (ISBF) return __bfloat162float(((const bf16*)p)[i]);
    return ((const float*)p)[i];
}

__device__ __forceinline__ float ldF(const void* __restrict__ p, long i, int isbf) {
    if (isbf) return __bfloat162float(((const bf16*)p)[i]);
    return ((const float*)p)[i];
}

__device__ __forceinline__ int detect_bf16(const void* asc) {
    // aff_scale_const == 4.0f. fp32 LE low uint16 of 0x40800000 is 0x0000;
    // bf16 encoding of 4.0 is 0x4080. Nonzero => bf16 inputs.
    return ((const unsigned short*)asc)[0] != 0;
}

// ---------------------------------------------------------------------------
// Kernel 1: bilinear 2x upsample (jax.image.resize == clamped bilinear at
// src = 0.5*o - 0.25), input -> fp32 ws [b][c][i][j]
// ---------------------------------------------------------------------------
__global__ __launch_bounds__(256) void upsample_kernel(const void* __restrict__ tin,
                                                       const void* __restrict__ asc,
                                                       float* __restrict__ fea) {
    int isbf = detect_bf16(asc);
    int idx = blockIdx.x * 256 + threadIdx.x;
    if (idx >= BB * 8 * HWSZ) return;
    int j = idx % WW;
    int rest = idx / WW;
    int i = rest % HH;
    int bc = rest / HH;  // b*8+c
    float sy = 0.5f * (float)i - 0.25f;
    float sx = 0.5f * (float)j - 0.25f;
    float y0f = floorf(sy), x0f = floorf(sx);
    float wy = sy - y0f, wx = sx - x0f;
    int y0 = (int)y0f, x0 = (int)x0f;
    int y0c = min(max(y0, 0), 119), y1c = min(max(y0 + 1, 0), 119);
    int x0c = min(max(x0, 0), 159), x1c = min(max(x0 + 1, 0), 159);
    long base = (long)bc * 120 * 160;
    float v00 = ldF(tin, base + y0c * 160 + x0c, isbf);
    float v01 = ldF(tin, base + y0c * 160 + x1c, isbf);
    float v10 = ldF(tin, base + y1c * 160 + x0c, isbf);
    float v11 = ldF(tin, base + y1c * 160 + x1c, isbf);
    fea[idx] = (1.f - wy) * ((1.f - wx) * v00 + wx * v01)
             + wy * ((1.f - wx) * v10 + wx * v11);
}

// ---------------------------------------------------------------------------
// Kernel 2: 3x3 conv 64->24 + bias, pad 1. Output pixel-major fp32:
// oa[((b*H+i)*W+j)*24 + c].
//
// Anti-spill structure (R3 post-mortem: LDS-weight version spilled, 3 GB
// scratch writes): 1 pixel/thread -> 24 accs + 9 ga live (~70 VGPR).
// Weights read via wave-UNIFORM global loads -> s_load through scalar cache,
// zero VGPR cost, co-issues with VALU. launch_bounds(256,4) caps VGPR at 128.
// ---------------------------------------------------------------------------
template<int ISBF>
__device__ __forceinline__ void conv_body(const void* __restrict__ g,
                                          const void* __restrict__ w,
                                          const void* __restrict__ bias,
                                          float* __restrict__ oa) {
    const int b = blockIdx.z;
    const int i0 = blockIdx.y * 16;
    const int j0 = blockIdx.x * 16;
    const int tx = threadIdx.x & 15;
    const int ty = threadIdx.x >> 4;   // 0..15

    __shared__ float gl[8][18][20];    // 8 in-ch chunk, 18x18 halo tile, pad->20

    float acc[NCO];
#pragma unroll
    for (int c = 0; c < NCO; c++) acc[c] = ldT<ISBF>(bias, c);

    for (int ci0 = 0; ci0 < CG; ci0 += 8) {
        __syncthreads();
        for (int idx = threadIdx.x; idx < 8 * 18 * 18; idx += 256) {
            int cc = idx / 324;
            int rem = idx - cc * 324;
            int r = rem / 18;
            int c2 = rem - r * 18;
            int gi = i0 - 1 + r;
            int gj = j0 - 1 + c2;
            float v = 0.f;
            if (gi >= 0 && gi < HH && gj >= 0 && gj < WW)
                v = ldT<ISBF>(g, ((long)(b * CG + ci0 + cc) * HH + gi) * WW + gj);
            gl[cc][r][c2] = v;
        }
        __syncthreads();
#pragma unroll
        for (int cc = 0; cc < 8; cc++) {
            float ga[9];
#pragma unroll
            for (int dy = 0; dy < 3; dy++)
#pragma unroll
                for (int dx = 0; dx < 3; dx++)
                    ga[dy * 3 + dx] = gl[cc][ty + dy][tx + dx];
#pragma unroll 6
            for (int co = 0; co < NCO; co++) {
                long wb = (long)(co * CG + ci0 + cc) * 9;  // wave-uniform
                float s = 0.f;
#pragma unroll
                for (int t = 0; t < 9; t++)
                    s += ldT<ISBF>(w, wb + t) * ga[t];
                acc[co] += s;
            }
        }
    }
    int i = i0 + ty, j = j0 + tx;
    float4* p = (float4*)&oa[(((size_t)b * HH + i) * WW + j) * NCO];
#pragma unroll
    for (int q = 0; q < 6; q++)
        p[q] = make_float4(acc[4 * q], acc[4 * q + 1], acc[4 * q + 2], acc[4 * q + 3]);
}

__global__ __launch_bounds__(256, 4) void conv_kernel(const void* __restrict__ g,
                                                      const void* __restrict__ w,
                                                      const void* __restrict__ bias,
                                                      const void* __restrict__ asc,
                                                      float* __restrict__ oa) {
    if (detect_bf16(asc)) conv_body<1>(g, w, bias, oa);
    else                  conv_body<0>(g, w, bias, oa);
}

// ---------------------------------------------------------------------------
// bilinear with zero padding outside (reference _bilinear_zeros semantics)
// ---------------------------------------------------------------------------
__device__ __forceinline__ float bil_zero_f32(const float* __restrict__ img,
                                              float x, float y, int Hh, int Wwd) {
    float x0f = floorf(x), y0f = floorf(y);
    float wx = x - x0f, wy = y - y0f;
    int x0 = (int)x0f, y0 = (int)y0f;
    float v00 = 0.f, v01 = 0.f, v10 = 0.f, v11 = 0.f;
    bool xv0 = (x0 >= 0) && (x0 < Wwd);
    bool xv1 = (x0 + 1 >= 0) && (x0 + 1 < Wwd);
    if (y0 >= 0 && y0 < Hh) {
        const float* r = img + (size_t)y0 * Wwd;
        if (xv0) v00 = r[x0];
        if (xv1) v01 = r[x0 + 1];
    }
    if (y0 + 1 >= 0 && y0 + 1 < Hh) {
        const float* r = img + (size_t)(y0 + 1) * Wwd;
        if (xv0) v10 = r[x0];
        if (xv1) v11 = r[x0 + 1];
    }
    return (1.f - wy) * ((1.f - wx) * v00 + wx * v01)
         + wy * ((1.f - wx) * v10 + wx * v11);
}

__device__ __forceinline__ float bil_zero_poly(const void* __restrict__ img, long base,
                                               float x, float y, int Hh, int Wwd, int isbf) {
    float x0f = floorf(x), y0f = floorf(y);
    float wx = x - x0f, wy = y - y0f;
    int x0 = (int)x0f, y0 = (int)y0f;
    float v00 = 0.f, v01 = 0.f, v10 = 0.f, v11 = 0.f;
    bool xv0 = (x0 >= 0) && (x0 < Wwd);
    bool xv1 = (x0 + 1 >= 0) && (x0 + 1 < Wwd);
    if (y0 >= 0 && y0 < Hh) {
        long r = base + (long)y0 * Wwd;
        if (xv0) v00 = ldF(img, r + x0, isbf);
        if (xv1) v01 = ldF(img, r + x0 + 1, isbf);
    }
    if (y0 + 1 >= 0 && y0 + 1 < Hh) {
        long r = base + (long)(y0 + 1) * Wwd;
        if (xv0) v10 = ldF(img, r + x0, isbf);
        if (xv1) v11 = ldF(img, r + x0 + 1, isbf);
    }
    return (1.f - wy) * ((1.f - wx) * v00 + wx * v01)
         + wy * ((1.f - wx) * v10 + wx * v11);
}

// ---------------------------------------------------------------------------
// Kernel 3: scrambled cosine-affinity gather + conf + TGASS + softmax + writes.
//   cos_w[b,c,i,j] = sum_{n<8} fea_up[b,n,i,j] * bil(fea_up[b, i/30], px, py)
//   source grid pixel (pi,qj) = ((i%30)*8 + j/40, (j%40)*8 + n)
//   px = oa[pi,qj,2c] + add, py = oa[pi,qj,2c+1] + add, add = (c<4 ? pi : qj)
// Outputs fp32 (reference dtype).
// ---------------------------------------------------------------------------
__global__ __launch_bounds__(256) void final_kernel(const float* __restrict__ oa,
                                                    const float* __restrict__ fea,
                                                    const void* __restrict__ conf_in,
                                                    const void* __restrict__ asc_p,
                                                    float* __restrict__ out) {
    int isbf = detect_bf16(asc_p);
    int idx = blockIdx.x * 256 + threadIdx.x;
    if (idx >= BB * HWSZ) return;
    int j = idx % WW;
    int rest = idx / WW;
    int i = rest % HH;
    int b = rest / HH;

    const float* feaB = fea + (size_t)b * 8 * HWSZ;
    float f[8];
#pragma unroll
    for (int n = 0; n < 8; n++)
        f[n] = feaB[(size_t)n * HWSZ + (size_t)i * WW + j];

    int c_img = i / 30;
    int pi = (i % 30) * 8 + j / 40;
    int pj0 = (j % 40) * 8;
    const float* feaC = feaB + (size_t)c_img * HWSZ;

    float cos_acc[8];
#pragma unroll
    for (int c = 0; c < 8; c++) cos_acc[c] = 0.f;

#pragma unroll
    for (int n = 0; n < 8; n++) {
        int qj = pj0 + n;
        const float4* oq = (const float4*)&oa[(((size_t)b * HH + pi) * WW + qj) * NCO];
        float4 o0 = oq[0], o1 = oq[1], o2 = oq[2], o3 = oq[3];
        float off[16] = {o0.x, o0.y, o0.z, o0.w, o1.x, o1.y, o1.z, o1.w,
                         o2.x, o2.y, o2.z, o2.w, o3.x, o3.y, o3.z, o3.w};
        float fn = f[n];
#pragma unroll
        for (int c = 0; c < 8; c++) {
            float add = (c < 4) ? (float)pi : (float)qj;
            float px = off[2 * c] + add;
            float py = off[2 * c + 1] + add;
            cos_acc[c] += fn * bil_zero_f32(feaC, px, py, HH, WW);
        }
    }

    const float4* op = (const float4*)&oa[(((size_t)b * HH + i) * WW + j) * NCO];
    float own[24];
#pragma unroll
    for (int q = 0; q < 6; q++) {
        float4 v = op[q];
        own[4 * q] = v.x; own[4 * q + 1] = v.y; own[4 * q + 2] = v.z; own[4 * q + 3] = v.w;
    }

    float asc = ldF(asc_p, 0, isbf) + 1e-8f;
    long cbase = (long)b * HWSZ;

    float a[8];
    float ssum = 0.f;
#pragma unroll
    for (int c = 0; c < 8; c++) {
        float v = own[16 + c] * cos_acc[c];
        v = tanhf(v) / asc;
        float py2 = own[2 * c] + (float)i;       // channel 0 = dy
        float px2 = own[2 * c + 1] + (float)j;   // channel 1 = dx
        float cf = bil_zero_poly(conf_in, cbase, px2, py2, HH, WW, isbf);
        v *= cf;
        a[c] = v;
        ssum += fabsf(v);
    }
    ssum += 1e-4f;
    ssum = fmaxf(ssum, 1.0f);
    float inv = 1.0f / ssum;
    float asum = 0.f;
#pragma unroll
    for (int c = 0; c < 8; c++) { a[c] *= inv; asum += a[c]; }
    float aref = 1.0f - asum;

    float vals[9];
#pragma unroll
    for (int c = 0; c < 4; c++) vals[c] = a[c];
    vals[4] = aref;
#pragma unroll
    for (int c = 4; c < 8; c++) vals[c + 1] = a[c];
    float m = vals[0];
#pragma unroll
    for (int k = 1; k < 9; k++) m = fmaxf(m, vals[k]);
    float es = 0.f;
#pragma unroll
    for (int k = 0; k < 9; k++) { vals[k] = __expf(vals[k] - m); es += vals[k]; }
    float ei = 1.0f / es;

    size_t pix = (size_t)i * WW + j;
    size_t base_o = (size_t)b * 18 * HWSZ + pix;
#pragma unroll
    for (int ch = 0; ch < 18; ch++) {
        float v;
        if (ch < 8) v = own[ch];
        else if (ch < 10) v = 0.f;
        else v = own[ch - 2];
        out[base_o + (size_t)ch * HWSZ] = v;
    }
    float* aff_out = out + (size_t)BB * 18 * HWSZ;
    size_t base_a = (size_t)b * 9 * HWSZ + pix;
#pragma unroll
    for (int k = 0; k < 9; k++)
        aff_out[base_a + (size_t)k * HWSZ] = vals[k] * ei;
}

// ---------------------------------------------------------------------------
extern "C" void kernel_launch(void* const* d_in, const int* in_sizes, int n_in,
                              void* d_out, int out_size, void* d_ws, size_t ws_size,
                              hipStream_t stream) {
    const void* guidance = d_in[0];
    const void* gtconf   = d_in[1];
    const void* tgt      = d_in[2];
    const void* conv_w   = d_in[3];
    const void* conv_b   = d_in[4];
    const void* asc      = d_in[5];

    float* oa  = (float*)d_ws;                        // B*H*W*24 fp32
    float* fea = oa + (size_t)BB * HWSZ * NCO;        // B*8*H*W fp32
    float* out = (float*)d_out;

    int n_up = BB * 8 * HWSZ;
    upsample_kernel<<<(n_up + 255) / 256, 256, 0, stream>>>(tgt, asc, fea);

    dim3 cgrid(WW / 16, HH / 16, BB);
    conv_kernel<<<cgrid, 256, 0, stream>>>(guidance, conv_w, conv_b, asc, oa);

    int n_fin = BB * HWSZ;
    final_kernel<<<(n_fin + 255) / 256, 256, 0, stream>>>(oa, fea, gtconf, asc, out);
}

// Round 5
// 660.151 us; speedup vs baseline: 3.7811x; 1.0779x over previous
//
#include <hip/hip_runtime.h>
#include <hip/hip_bf16.h>

typedef __hip_bfloat16 bf16;

#define BB 4
#define HH 240
#define WW 320
#define CG 64
#define NCO 24
#define HWSZ (HH*WW)

// Runtime-polymorphic input load (compile-time flavor via template).
template<int ISBF>
__device__ __forceinline__ float ldT(const void* __restrict__ p, long i) {
    if (ISBF) return __bfloat162float(((const bf16*)p)[i]);
    return ((const float*)p)[i];
}

__device__ __forceinline__ float ldF(const void* __restrict__ p, long i, int isbf) {
    if (isbf) return __bfloat162float(((const bf16*)p)[i]);
    return ((const float*)p)[i];
}

__device__ __forceinline__ int detect_bf16(const void* asc) {
    // aff_scale_const == 4.0f. fp32 LE low uint16 of 0x40800000 is 0x0000;
    // bf16 encoding of 4.0 is 0x4080. Nonzero => bf16 inputs.
    return ((const unsigned short*)asc)[0] != 0;
}

// ---------------------------------------------------------------------------
// Kernel 1: bilinear 2x upsample (jax.image.resize == clamped bilinear at
// src = 0.5*o - 0.25), input -> fp32 ws [b][c][i][j]
// ---------------------------------------------------------------------------
__global__ __launch_bounds__(256) void upsample_kernel(const void* __restrict__ tin,
                                                       const void* __restrict__ asc,
                                                       float* __restrict__ fea) {
    int isbf = detect_bf16(asc);
    int idx = blockIdx.x * 256 + threadIdx.x;
    if (idx >= BB * 8 * HWSZ) return;
    int j = idx % WW;
    int rest = idx / WW;
    int i = rest % HH;
    int bc = rest / HH;  // b*8+c
    float sy = 0.5f * (float)i - 0.25f;
    float sx = 0.5f * (float)j - 0.25f;
    float y0f = floorf(sy), x0f = floorf(sx);
    float wy = sy - y0f, wx = sx - x0f;
    int y0 = (int)y0f, x0 = (int)x0f;
    int y0c = min(max(y0, 0), 119), y1c = min(max(y0 + 1, 0), 119);
    int x0c = min(max(x0, 0), 159), x1c = min(max(x0 + 1, 0), 159);
    long base = (long)bc * 120 * 160;
    float v00 = ldF(tin, base + y0c * 160 + x0c, isbf);
    float v01 = ldF(tin, base + y0c * 160 + x1c, isbf);
    float v10 = ldF(tin, base + y1c * 160 + x0c, isbf);
    float v11 = ldF(tin, base + y1c * 160 + x1c, isbf);
    fea[idx] = (1.f - wy) * ((1.f - wx) * v00 + wx * v01)
             + wy * ((1.f - wx) * v10 + wx * v11);
}

// ---------------------------------------------------------------------------
// Kernel 2: 3x3 conv 64->24 + bias, pad 1. Output pixel-major fp32:
// oa[((b*H+i)*W+j)*24 + c].
//
// R4 post-mortem: SGPR weight loads put 13824 s_load + lgkm waits in the
// per-wave instruction stream (1:1 with FMA). R5: stage the 8-cin weight
// slice (1728 floats, 6.9 KB) in LDS per chunk; inner loop reads it via
// broadcast ds_read (wave-uniform address -> no bank conflict, no SALU).
// 1 px/thread + unroll-4 co-loop keeps ~90 VGPR (R3's spill was 2px +
// hoisting 100+ weight reads).
// ---------------------------------------------------------------------------
template<int ISBF>
__device__ __forceinline__ void conv_body(const void* __restrict__ g,
                                          const void* __restrict__ w,
                                          const void* __restrict__ bias,
                                          float* __restrict__ oa) {
    const int b = blockIdx.z;
    const int i0 = blockIdx.y * 16;
    const int j0 = blockIdx.x * 16;
    const int tx = threadIdx.x & 15;
    const int ty = threadIdx.x >> 4;   // 0..15

    __shared__ float gl[8][18][20];    // 8 in-ch chunk, 18x18 halo tile, pad->20
    __shared__ float wl[8][NCO][10];   // per-chunk weights [cc][co][tap]

    float acc[NCO];
#pragma unroll
    for (int c = 0; c < NCO; c++) acc[c] = ldT<ISBF>(bias, c);

    for (int ci0 = 0; ci0 < CG; ci0 += 8) {
        __syncthreads();
        // stage weight slice: idx = (co*8+cc)*9+t, coalesced-ish global reads
        for (int idx = threadIdx.x; idx < 8 * NCO * 9; idx += 256) {
            int t = idx % 9;
            int rest = idx / 9;
            int cc = rest & 7;
            int co = rest >> 3;
            wl[cc][co][t] = ldT<ISBF>(w, (long)(co * CG + ci0 + cc) * 9 + t);
        }
        // stage guidance tile with halo (zero padded)
        for (int idx = threadIdx.x; idx < 8 * 18 * 18; idx += 256) {
            int cc = idx / 324;
            int rem = idx - cc * 324;
            int r = rem / 18;
            int c2 = rem - r * 18;
            int gi = i0 - 1 + r;
            int gj = j0 - 1 + c2;
            float v = 0.f;
            if (gi >= 0 && gi < HH && gj >= 0 && gj < WW)
                v = ldT<ISBF>(g, ((long)(b * CG + ci0 + cc) * HH + gi) * WW + gj);
            gl[cc][r][c2] = v;
        }
        __syncthreads();
#pragma unroll
        for (int cc = 0; cc < 8; cc++) {
            float ga[9];
#pragma unroll
            for (int dy = 0; dy < 3; dy++)
#pragma unroll
                for (int dx = 0; dx < 3; dx++)
                    ga[dy * 3 + dx] = gl[cc][ty + dy][tx + dx];
#pragma unroll 4
            for (int co = 0; co < NCO; co++) {
                float s = 0.f;
#pragma unroll
                for (int t = 0; t < 9; t++)
                    s += wl[cc][co][t] * ga[t];
                acc[co] += s;
            }
        }
    }
    int i = i0 + ty, j = j0 + tx;
    float4* p = (float4*)&oa[(((size_t)b * HH + i) * WW + j) * NCO];
#pragma unroll
    for (int q = 0; q < 6; q++)
        p[q] = make_float4(acc[4 * q], acc[4 * q + 1], acc[4 * q + 2], acc[4 * q + 3]);
}

__global__ __launch_bounds__(256, 4) void conv_kernel(const void* __restrict__ g,
                                                      const void* __restrict__ w,
                                                      const void* __restrict__ bias,
                                                      const void* __restrict__ asc,
                                                      float* __restrict__ oa) {
    if (detect_bf16(asc)) conv_body<1>(g, w, bias, oa);
    else                  conv_body<0>(g, w, bias, oa);
}

// ---------------------------------------------------------------------------
// bilinear with zero padding outside (reference _bilinear_zeros semantics)
// ---------------------------------------------------------------------------
__device__ __forceinline__ float bil_zero_f32(const float* __restrict__ img,
                                              float x, float y, int Hh, int Wwd) {
    float x0f = floorf(x), y0f = floorf(y);
    float wx = x - x0f, wy = y - y0f;
    int x0 = (int)x0f, y0 = (int)y0f;
    float v00 = 0.f, v01 = 0.f, v10 = 0.f, v11 = 0.f;
    bool xv0 = (x0 >= 0) && (x0 < Wwd);
    bool xv1 = (x0 + 1 >= 0) && (x0 + 1 < Wwd);
    if (y0 >= 0 && y0 < Hh) {
        const float* r = img + (size_t)y0 * Wwd;
        if (xv0) v00 = r[x0];
        if (xv1) v01 = r[x0 + 1];
    }
    if (y0 + 1 >= 0 && y0 + 1 < Hh) {
        const float* r = img + (size_t)(y0 + 1) * Wwd;
        if (xv0) v10 = r[x0];
        if (xv1) v11 = r[x0 + 1];
    }
    return (1.f - wy) * ((1.f - wx) * v00 + wx * v01)
         + wy * ((1.f - wx) * v10 + wx * v11);
}

__device__ __forceinline__ float bil_zero_poly(const void* __restrict__ img, long base,
                                               float x, float y, int Hh, int Wwd, int isbf) {
    float x0f = floorf(x), y0f = floorf(y);
    float wx = x - x0f, wy = y - y0f;
    int x0 = (int)x0f, y0 = (int)y0f;
    float v00 = 0.f, v01 = 0.f, v10 = 0.f, v11 = 0.f;
    bool xv0 = (x0 >= 0) && (x0 < Wwd);
    bool xv1 = (x0 + 1 >= 0) && (x0 + 1 < Wwd);
    if (y0 >= 0 && y0 < Hh) {
        long r = base + (long)y0 * Wwd;
        if (xv0) v00 = ldF(img, r + x0, isbf);
        if (xv1) v01 = ldF(img, r + x0 + 1, isbf);
    }
    if (y0 + 1 >= 0 && y0 + 1 < Hh) {
        long r = base + (long)(y0 + 1) * Wwd;
        if (xv0) v10 = ldF(img, r + x0, isbf);
        if (xv1) v11 = ldF(img, r + x0 + 1, isbf);
    }
    return (1.f - wy) * ((1.f - wx) * v00 + wx * v01)
         + wy * ((1.f - wx) * v10 + wx * v11);
}

// ---------------------------------------------------------------------------
// Kernel 3: scrambled cosine-affinity gather + conf + TGASS + softmax + writes.
//   cos_w[b,c,i,j] = sum_{n<8} fea_up[b,n,i,j] * bil(fea_up[b, i/30], px, py)
//   source grid pixel (pi,qj) = ((i%30)*8 + j/40, (j%40)*8 + n)
//   px = oa[pi,qj,2c] + add, py = oa[pi,qj,2c+1] + add, add = (c<4 ? pi : qj)
// Outputs fp32 (reference dtype).
// ---------------------------------------------------------------------------
__global__ __launch_bounds__(256) void final_kernel(const float* __restrict__ oa,
                                                    const float* __restrict__ fea,
                                                    const void* __restrict__ conf_in,
                                                    const void* __restrict__ asc_p,
                                                    float* __restrict__ out) {
    int isbf = detect_bf16(asc_p);
    int idx = blockIdx.x * 256 + threadIdx.x;
    if (idx >= BB * HWSZ) return;
    int j = idx % WW;
    int rest = idx / WW;
    int i = rest % HH;
    int b = rest / HH;

    const float* feaB = fea + (size_t)b * 8 * HWSZ;
    float f[8];
#pragma unroll
    for (int n = 0; n < 8; n++)
        f[n] = feaB[(size_t)n * HWSZ + (size_t)i * WW + j];

    int c_img = i / 30;
    int pi = (i % 30) * 8 + j / 40;
    int pj0 = (j % 40) * 8;
    const float* feaC = feaB + (size_t)c_img * HWSZ;

    float cos_acc[8];
#pragma unroll
    for (int c = 0; c < 8; c++) cos_acc[c] = 0.f;

#pragma unroll
    for (int n = 0; n < 8; n++) {
        int qj = pj0 + n;
        const float4* oq = (const float4*)&oa[(((size_t)b * HH + pi) * WW + qj) * NCO];
        float4 o0 = oq[0], o1 = oq[1], o2 = oq[2], o3 = oq[3];
        float off[16] = {o0.x, o0.y, o0.z, o0.w, o1.x, o1.y, o1.z, o1.w,
                         o2.x, o2.y, o2.z, o2.w, o3.x, o3.y, o3.z, o3.w};
        float fn = f[n];
#pragma unroll
        for (int c = 0; c < 8; c++) {
            float add = (c < 4) ? (float)pi : (float)qj;
            float px = off[2 * c] + add;
            float py = off[2 * c + 1] + add;
            cos_acc[c] += fn * bil_zero_f32(feaC, px, py, HH, WW);
        }
    }

    const float4* op = (const float4*)&oa[(((size_t)b * HH + i) * WW + j) * NCO];
    float own[24];
#pragma unroll
    for (int q = 0; q < 6; q++) {
        float4 v = op[q];
        own[4 * q] = v.x; own[4 * q + 1] = v.y; own[4 * q + 2] = v.z; own[4 * q + 3] = v.w;
    }

    float asc = ldF(asc_p, 0, isbf) + 1e-8f;
    long cbase = (long)b * HWSZ;

    float a[8];
    float ssum = 0.f;
#pragma unroll
    for (int c = 0; c < 8; c++) {
        float v = own[16 + c] * cos_acc[c];
        v = tanhf(v) / asc;
        float py2 = own[2 * c] + (float)i;       // channel 0 = dy
        float px2 = own[2 * c + 1] + (float)j;   // channel 1 = dx
        float cf = bil_zero_poly(conf_in, cbase, px2, py2, HH, WW, isbf);
        v *= cf;
        a[c] = v;
        ssum += fabsf(v);
    }
    ssum += 1e-4f;
    ssum = fmaxf(ssum, 1.0f);
    float inv = 1.0f / ssum;
    float asum = 0.f;
#pragma unroll
    for (int c = 0; c < 8; c++) { a[c] *= inv; asum += a[c]; }
    float aref = 1.0f - asum;

    float vals[9];
#pragma unroll
    for (int c = 0; c < 4; c++) vals[c] = a[c];
    vals[4] = aref;
#pragma unroll
    for (int c = 4; c < 8; c++) vals[c + 1] = a[c];
    float m = vals[0];
#pragma unroll
    for (int k = 1; k < 9; k++) m = fmaxf(m, vals[k]);
    float es = 0.f;
#pragma unroll
    for (int k = 0; k < 9; k++) { vals[k] = __expf(vals[k] - m); es += vals[k]; }
    float ei = 1.0f / es;

    size_t pix = (size_t)i * WW + j;
    size_t base_o = (size_t)b * 18 * HWSZ + pix;
#pragma unroll
    for (int ch = 0; ch < 18; ch++) {
        float v;
        if (ch < 8) v = own[ch];
        else if (ch < 10) v = 0.f;
        else v = own[ch - 2];
        out[base_o + (size_t)ch * HWSZ] = v;
    }
    float* aff_out = out + (size_t)BB * 18 * HWSZ;
    size_t base_a = (size_t)b * 9 * HWSZ + pix;
#pragma unroll
    for (int k = 0; k < 9; k++)
        aff_out[base_a + (size_t)k * HWSZ] = vals[k] * ei;
}

// ---------------------------------------------------------------------------
extern "C" void kernel_launch(void* const* d_in, const int* in_sizes, int n_in,
                              void* d_out, int out_size, void* d_ws, size_t ws_size,
                              hipStream_t stream) {
    const void* guidance = d_in[0];
    const void* gtconf   = d_in[1];
    const void* tgt      = d_in[2];
    const void* conv_w   = d_in[3];
    const void* conv_b   = d_in[4];
    const void* asc      = d_in[5];

    float* oa  = (float*)d_ws;                        // B*H*W*24 fp32
    float* fea = oa + (size_t)BB * HWSZ * NCO;        // B*8*H*W fp32
    float* out = (float*)d_out;

    int n_up = BB * 8 * HWSZ;
    upsample_kernel<<<(n_up + 255) / 256, 256, 0, stream>>>(tgt, asc, fea);

    dim3 cgrid(WW / 16, HH / 16, BB);
    conv_kernel<<<cgrid, 256, 0, stream>>>(guidance, conv_w, conv_b, asc, oa);

    int n_fin = BB * HWSZ;
    final_kernel<<<(n_fin + 255) / 256, 256, 0, stream>>>(oa, fea, gtconf, asc, out);
}